// Round 9
// baseline (468.566 us; speedup 1.0000x reference)
//
#include <hip/hip_runtime.h>
#include <hip/hip_bf16.h>

#define PP 8192
#define UU 4096
#define EE 4096
#define BB 1024

using f32x4  = __attribute__((ext_vector_type(4))) float;
using u32x4  = __attribute__((ext_vector_type(4))) unsigned int;
using u32x2  = __attribute__((ext_vector_type(2))) unsigned int;
using bf16x8 = __attribute__((ext_vector_type(8))) short;
typedef __hip_bfloat16 bf16_t;

__device__ __forceinline__ unsigned cvt2(float a, float b){
  unsigned r;
  asm("v_cvt_pk_bf16_f32 %0, %1, %2" : "=v"(r) : "v"(a), "v"(b));
  return r;
}

__device__ __forceinline__ void gload16(const void* g, void* l){
  __builtin_amdgcn_global_load_lds((const __attribute__((address_space(1))) void*)g,
                                   (__attribute__((address_space(3))) void*)l, 16, 0, 0);
}

struct Job {
  const float*  A;      // [M][K] f32
  const bf16_t* Bt;     // [128][K] bf16 (B transposed)
  const float*  add;    // epilogue add (or pe for sigmoid mode); may be null
  const float*  bvec;   // sigmoid bias [128]; null otherwise
  float*        outF;   // f32 out [M][128]; may be null
  bf16_t*       outT;   // transposed bf16 out [128][stride]; may be null
  int           outTstride;
  float         scale;  // final = add + scale*C  (mode 0)
  int           K;
  int           nb;     // number of row tiles (16 for gemm_slab, 32 for others)
  int           mode;   // 0 linear, 1 sigmoid-gate
};

#define WAITV(n) asm volatile("s_waitcnt vmcnt(" #n ")" ::: "memory")
#define LGKM0    asm volatile("s_waitcnt lgkmcnt(0)" ::: "memory")
#define SBAR     __builtin_amdgcn_sched_barrier(0)
#define BAR      __builtin_amdgcn_s_barrier()

// ============== SLAB GEMM (phase B): per-wave LINEAR 4KB row runs ==============
// BM=16 rows, Kslab=1024, 512 thr = 8 waves (8-way K-split within slab).
// A: global f32 -> regs (sequential 4KB runs/row) -> bf16 -> swizzled LDS [16][1024].
// B: 2MB, L2-hot -> fragment loads straight from global, 2-set register prefetch.
__global__ __launch_bounds__(512, 2) void gemm_slab(Job j0, Job j1, Job j2){
  __shared__ char smem[65536];
  int bid = blockIdx.x;
  Job j = j0;
  if (bid >= j.nb){ bid -= j.nb; j = j1; if (bid >= j.nb){ bid -= j.nb; j = j2; } }
  const int K = j.K;
  const int S = K >> 10;                 // 1024-k slabs (8 for K=8192)
  const int m0 = bid << 4;
  const int tid = threadIdx.x;
  const int lane = tid & 63;
  const int wid = tid >> 6;              // wave = K-octant of the slab

  // ---- staging: thread t owns row t>>5, 128B f32 chunk (t&31); 8 sequential 16B loads ----
  const int sr = tid >> 5;
  const int sc = tid & 31;
  const char* asrc = (const char*)j.A + (size_t)(m0 + sr)*(size_t)K*4 + (unsigned)(sc*128);
  unsigned wr0, wr1, wr2, wr3;
  {
    unsigned swz = (unsigned)(sr & 7) << 4;
    wr0 = (unsigned)(sr*2048) + (((unsigned)(sc*64 +  0)) ^ swz);
    wr1 = (unsigned)(sr*2048) + (((unsigned)(sc*64 + 16)) ^ swz);
    wr2 = (unsigned)(sr*2048) + (((unsigned)(sc*64 + 32)) ^ swz);
    wr3 = (unsigned)(sr*2048) + (((unsigned)(sc*64 + 48)) ^ swz);
  }

  // ---- A fragment read addrs (bf16 LDS, one ds_read_b128 per kstep) ----
  unsigned ard0, ard1, ard2, ard3;
  {
    unsigned row = lane & 15, g = lane >> 4;
    unsigned swz = (row & 7) << 4;
    ard0 = row*2048 + (((unsigned)(wid*256 +   0 + g*16)) ^ swz);
    ard1 = row*2048 + (((unsigned)(wid*256 +  64 + g*16)) ^ swz);
    ard2 = row*2048 + (((unsigned)(wid*256 + 128 + g*16)) ^ swz);
    ard3 = row*2048 + (((unsigned)(wid*256 + 192 + g*16)) ^ swz);
  }

  // ---- B fragment pointers (8 n0-frags), advanced 2048B per slab ----
  const char* bp[8];
  {
    unsigned row = lane & 15, g = lane >> 4;
    #pragma unroll
    for (int n0 = 0; n0 < 8; ++n0)
      bp[n0] = (const char*)j.Bt + (size_t)(n0*16 + row)*(size_t)K*2
             + (unsigned)(wid*256 + g*16);
  }

  f32x4 acc[8];
  const f32x4 fzero = {0.f,0.f,0.f,0.f};
  #pragma unroll
  for (int i = 0; i < 8; ++i) acc[i] = fzero;

  bf16x8 Bc[8], Bn[8];
  f32x4 sv0,sv1,sv2,sv3,sv4,sv5,sv6,sv7;

#define AISS() do { asm volatile( \
    "global_load_dwordx4 %0, %8, off\n\t" \
    "global_load_dwordx4 %1, %8, off offset:16\n\t" \
    "global_load_dwordx4 %2, %8, off offset:32\n\t" \
    "global_load_dwordx4 %3, %8, off offset:48\n\t" \
    "global_load_dwordx4 %4, %8, off offset:64\n\t" \
    "global_load_dwordx4 %5, %8, off offset:80\n\t" \
    "global_load_dwordx4 %6, %8, off offset:96\n\t" \
    "global_load_dwordx4 %7, %8, off offset:112" \
    : "=&v"(sv0),"=&v"(sv1),"=&v"(sv2),"=&v"(sv3), \
      "=&v"(sv4),"=&v"(sv5),"=&v"(sv6),"=&v"(sv7) \
    : "v"(asrc) : "memory"); asrc += 4096; } while(0)

#define AWRITE(BO) do { \
    union { bf16x8 v; unsigned u[4]; } q0,q1,q2,q3; \
    q0.u[0]=cvt2(sv0.x,sv0.y); q0.u[1]=cvt2(sv0.z,sv0.w); q0.u[2]=cvt2(sv1.x,sv1.y); q0.u[3]=cvt2(sv1.z,sv1.w); \
    q1.u[0]=cvt2(sv2.x,sv2.y); q1.u[1]=cvt2(sv2.z,sv2.w); q1.u[2]=cvt2(sv3.x,sv3.y); q1.u[3]=cvt2(sv3.z,sv3.w); \
    q2.u[0]=cvt2(sv4.x,sv4.y); q2.u[1]=cvt2(sv4.z,sv4.w); q2.u[2]=cvt2(sv5.x,sv5.y); q2.u[3]=cvt2(sv5.z,sv5.w); \
    q3.u[0]=cvt2(sv6.x,sv6.y); q3.u[1]=cvt2(sv6.z,sv6.w); q3.u[2]=cvt2(sv7.x,sv7.y); q3.u[3]=cvt2(sv7.z,sv7.w); \
    asm volatile("ds_write_b128 %0, %1" :: "v"((BO)+wr0), "v"(q0.v) : "memory"); \
    asm volatile("ds_write_b128 %0, %1" :: "v"((BO)+wr1), "v"(q1.v) : "memory"); \
    asm volatile("ds_write_b128 %0, %1" :: "v"((BO)+wr2), "v"(q2.v) : "memory"); \
    asm volatile("ds_write_b128 %0, %1" :: "v"((BO)+wr3), "v"(q3.v) : "memory"); } while(0)

#define BLD(DST, PTR, OFFS) asm volatile("global_load_dwordx4 %0, %1, off offset:" OFFS \
    : "=&v"(DST) : "v"(PTR) : "memory")
#define BISS(SET, OFFS) do { \
    BLD(SET[0], bp[0], OFFS); BLD(SET[1], bp[1], OFFS); \
    BLD(SET[2], bp[2], OFFS); BLD(SET[3], bp[3], OFFS); \
    BLD(SET[4], bp[4], OFFS); BLD(SET[5], bp[5], OFFS); \
    BLD(SET[6], bp[6], OFFS); BLD(SET[7], bp[7], OFFS); } while(0)

  // ds_read A-frag first, then single combined wait (vm for B-set + lgkm for A-frag)
#define KSTEP(ARD, SET, WN) do { \
    bf16x8 afr_; unsigned aa_ = bo + (ARD); \
    asm volatile("ds_read_b128 %0, %1" : "=v"(afr_) : "v"(aa_)); \
    asm volatile("s_waitcnt vmcnt(" #WN ") lgkmcnt(0)" ::: "memory"); \
    __builtin_amdgcn_sched_barrier(0); \
    acc[0] = __builtin_amdgcn_mfma_f32_16x16x32_bf16(afr_, SET[0], acc[0], 0,0,0); \
    acc[1] = __builtin_amdgcn_mfma_f32_16x16x32_bf16(afr_, SET[1], acc[1], 0,0,0); \
    acc[2] = __builtin_amdgcn_mfma_f32_16x16x32_bf16(afr_, SET[2], acc[2], 0,0,0); \
    acc[3] = __builtin_amdgcn_mfma_f32_16x16x32_bf16(afr_, SET[3], acc[3], 0,0,0); \
    acc[4] = __builtin_amdgcn_mfma_f32_16x16x32_bf16(afr_, SET[4], acc[4], 0,0,0); \
    acc[5] = __builtin_amdgcn_mfma_f32_16x16x32_bf16(afr_, SET[5], acc[5], 0,0,0); \
    acc[6] = __builtin_amdgcn_mfma_f32_16x16x32_bf16(afr_, SET[6], acc[6], 0,0,0); \
    acc[7] = __builtin_amdgcn_mfma_f32_16x16x32_bf16(afr_, SET[7], acc[7], 0,0,0); } while(0)

  // prologue: stage slab 0
  AISS(); WAITV(0); AWRITE(0u); LGKM0; BAR;

  for (int s = 0; s < S; ++s){
    const unsigned bo = (unsigned)(s & 1) << 15;
    const bool st = (s + 1 < S);
    BISS(Bc, "0");
    BISS(Bn, "64");
    KSTEP(ard0, Bc, 8);
    BISS(Bc, "128");
    KSTEP(ard1, Bn, 8);
    BISS(Bn, "192");
    if (st){
      AISS();
      KSTEP(ard2, Bc, 16);
      KSTEP(ard3, Bn, 8);
      WAITV(0);
      AWRITE(bo ^ 32768u);
      LGKM0;
    } else {
      KSTEP(ard2, Bc, 8);
      KSTEP(ard3, Bn, 0);
    }
    BAR;
    #pragma unroll
    for (int n0 = 0; n0 < 8; ++n0) bp[n0] += 2048;
  }

  // ---- 8-way wave reduction via LDS (reuses both slab buffers: 8 x 8KB) ----
  __syncthreads();
  float* red = (float*)smem;
  {
    unsigned base = (unsigned)wid * 2048u;
    unsigned rr = (unsigned)((lane >> 4) << 2), cc = (unsigned)(lane & 15);
    #pragma unroll
    for (int n0 = 0; n0 < 8; ++n0)
      #pragma unroll
      for (int q = 0; q < 4; ++q)
        red[base + (rr + q)*128 + n0*16 + cc] = acc[n0][q];
  }
  __syncthreads();
  f32x4 sum;
  {
    unsigned o = (unsigned)tid * 4u;
    sum = *(const f32x4*)&red[o];
    #pragma unroll
    for (int w = 1; w < 8; ++w){
      f32x4 t = *(const f32x4*)&red[w*2048u + o];
      sum.x += t.x; sum.y += t.y; sum.z += t.z; sum.w += t.w;
    }
    sum.x *= j.scale; sum.y *= j.scale; sum.z *= j.scale; sum.w *= j.scale;
    int row = tid >> 5, cb = (tid & 31) * 4;
    size_t gp = (size_t)(m0 + row);
    if (j.add){
      f32x4 a = *(const f32x4*)&j.add[gp*128 + cb];
      sum.x += a.x; sum.y += a.y; sum.z += a.z; sum.w += a.w;
    }
    if (j.outF) *(f32x4*)&j.outF[gp*128 + cb] = sum;
  }
  if (j.outT){
    __syncthreads();
    *(f32x4*)&red[(unsigned)tid*4u] = sum;   // fin[16][128] in first 8KB
    __syncthreads();
    int col = tid >> 2, rg = tid & 3;
    float f0 = red[(rg*4+0)*128 + col], f1 = red[(rg*4+1)*128 + col];
    float f2 = red[(rg*4+2)*128 + col], f3 = red[(rg*4+3)*128 + col];
    u32x2 wv; wv.x = cvt2(f0, f1); wv.y = cvt2(f2, f3);
    bf16_t* dst = j.outT + (size_t)col * (size_t)j.outTstride + (m0 + rg*4);
    *(u32x2*)dst = wv;
  }
#undef AISS
#undef AWRITE
#undef BLD
#undef BISS
#undef KSTEP
}

// ============ REG-STAGED GEMM (phase C) — round-8 verified ============
#define RSBUF 24576

__global__ __launch_bounds__(256, 2) void gemm_rs(Job j0, Job j1, Job j2){
  __shared__ char smem[2*RSBUF];
  int bid = blockIdx.x;
  Job j = j0;
  if (bid >= j.nb){ bid -= j.nb; j = j1; if (bid >= j.nb){ bid -= j.nb; j = j2; } }
  const int K = j.K;
  const int T = K >> 6;
  const int m0 = bid << 5;
  const int tid = threadIdx.x;
  const int lane = tid & 63;
  const int wid = tid >> 6;
  const int wm = wid >> 1, wk = wid & 1;

  const int srow = tid >> 3;
  const int scol = (tid & 7) * 16;
  const char* ap  = (const char*)j.A  + (size_t)(m0 + srow)*(size_t)K*4 + (unsigned)scol;
  const char* bq0 = (const char*)j.Bt + (size_t)(srow      )*(size_t)K*2 + (unsigned)scol;
  const char* bq1 = (const char*)j.Bt + (size_t)(srow +  32)*(size_t)K*2 + (unsigned)scol;
  const char* bq2 = (const char*)j.Bt + (size_t)(srow +  64)*(size_t)K*2 + (unsigned)scol;
  const char* bq3 = (const char*)j.Bt + (size_t)(srow +  96)*(size_t)K*2 + (unsigned)scol;

  const unsigned aswzw = (unsigned)((srow & 15) << 4);
  const unsigned wa0 = (unsigned)(srow*256) + ((unsigned)scol ^ aswzw);
  const unsigned wa1 = (unsigned)(srow*256) + (((unsigned)scol + 128u) ^ aswzw);
  const unsigned bswzw = (unsigned)((srow & 7) << 4);
  const unsigned wb0 = 8192u + (unsigned)(srow*128) + ((unsigned)scol ^ bswzw);

  const int arow = wm*16 + (lane & 15);
  const unsigned acb  = (unsigned)(wk*128 + ((lane>>4) * 32));
  const unsigned aswz = (unsigned)((arow & 15) << 4);
  const unsigned a_rd0 = arow*256 + (acb ^ aswz);
  const unsigned a_rd1 = arow*256 + ((acb + 16) ^ aswz);
  unsigned b_rd[8];
  #pragma unroll
  for (int n0 = 0; n0 < 8; ++n0){
    int n = n0*16 + (lane & 15);
    unsigned c = (unsigned)(wk*64 + ((lane>>4) * 16));
    b_rd[n0] = 8192u + n*128 + (c ^ ((n & 7) << 4));
  }

  f32x4 acc[8];
  const f32x4 fzero = {0.f,0.f,0.f,0.f};
  #pragma unroll
  for (int i = 0; i < 8; ++i) acc[i] = fzero;

  f32x4 eA0,eA1,eB0,eB1,eB2,eB3, oA0,oA1,oB0,oB1,oB2,oB3;

#define RS_ISSUE(A0,A1,B0,B1,B2,B3) do { \
    asm volatile("global_load_dwordx4 %0, %2, off\n\t" \
                 "global_load_dwordx4 %1, %2, off offset:128" \
      : "=&v"(A0), "=&v"(A1) : "v"(ap) : "memory"); \
    asm volatile("global_load_dwordx4 %0, %1, off" : "=&v"(B0) : "v"(bq0) : "memory"); \
    asm volatile("global_load_dwordx4 %0, %1, off" : "=&v"(B1) : "v"(bq1) : "memory"); \
    asm volatile("global_load_dwordx4 %0, %1, off" : "=&v"(B2) : "v"(bq2) : "memory"); \
    asm volatile("global_load_dwordx4 %0, %1, off" : "=&v"(B3) : "v"(bq3) : "memory"); \
    ap += 256; bq0 += 128; bq1 += 128; bq2 += 128; bq3 += 128; } while(0)

#define RS_DSW(bo,A0,A1,B0,B1,B2,B3) do { \
    asm volatile("ds_write_b128 %0, %1" :: "v"((bo) + wa0), "v"(A0) : "memory"); \
    asm volatile("ds_write_b128 %0, %1" :: "v"((bo) + wa1), "v"(A1) : "memory"); \
    asm volatile("ds_write_b128 %0, %1"              :: "v"((bo) + wb0), "v"(B0) : "memory"); \
    asm volatile("ds_write_b128 %0, %1 offset:4096"  :: "v"((bo) + wb0), "v"(B1) : "memory"); \
    asm volatile("ds_write_b128 %0, %1 offset:8192"  :: "v"((bo) + wb0), "v"(B2) : "memory"); \
    asm volatile("ds_write_b128 %0, %1 offset:12288" :: "v"((bo) + wb0), "v"(B3) : "memory"); } while(0)

  auto COMP = [&](unsigned bo){
    f32x4 a0, a1;
    asm volatile("ds_read_b128 %0, %1" : "=v"(a0) : "v"(bo + a_rd0));
    asm volatile("ds_read_b128 %0, %1" : "=v"(a1) : "v"(bo + a_rd1));
    bf16x8 b0,b1,b2,b3,b4,b5,b6,b7;
    asm volatile("ds_read_b128 %0, %1" : "=v"(b0) : "v"(bo + b_rd[0]));
    asm volatile("ds_read_b128 %0, %1" : "=v"(b1) : "v"(bo + b_rd[1]));
    asm volatile("ds_read_b128 %0, %1" : "=v"(b2) : "v"(bo + b_rd[2]));
    asm volatile("ds_read_b128 %0, %1" : "=v"(b3) : "v"(bo + b_rd[3]));
    asm volatile("ds_read_b128 %0, %1" : "=v"(b4) : "v"(bo + b_rd[4]));
    asm volatile("ds_read_b128 %0, %1" : "=v"(b5) : "v"(bo + b_rd[5]));
    asm volatile("ds_read_b128 %0, %1" : "=v"(b6) : "v"(bo + b_rd[6]));
    asm volatile("ds_read_b128 %0, %1" : "=v"(b7) : "v"(bo + b_rd[7]));
    LGKM0;
    SBAR;
    union { bf16x8 v; unsigned u[4]; } af;
    af.u[0] = cvt2(a0.x, a0.y);
    af.u[1] = cvt2(a0.z, a0.w);
    af.u[2] = cvt2(a1.x, a1.y);
    af.u[3] = cvt2(a1.z, a1.w);
    acc[0] = __builtin_amdgcn_mfma_f32_16x16x32_bf16(af.v, b0, acc[0], 0,0,0);
    acc[1] = __builtin_amdgcn_mfma_f32_16x16x32_bf16(af.v, b1, acc[1], 0,0,0);
    acc[2] = __builtin_amdgcn_mfma_f32_16x16x32_bf16(af.v, b2, acc[2], 0,0,0);
    acc[3] = __builtin_amdgcn_mfma_f32_16x16x32_bf16(af.v, b3, acc[3], 0,0,0);
    acc[4] = __builtin_amdgcn_mfma_f32_16x16x32_bf16(af.v, b4, acc[4], 0,0,0);
    acc[5] = __builtin_amdgcn_mfma_f32_16x16x32_bf16(af.v, b5, acc[5], 0,0,0);
    acc[6] = __builtin_amdgcn_mfma_f32_16x16x32_bf16(af.v, b6, acc[6], 0,0,0);
    acc[7] = __builtin_amdgcn_mfma_f32_16x16x32_bf16(af.v, b7, acc[7], 0,0,0);
  };

  RS_ISSUE(eA0,eA1,eB0,eB1,eB2,eB3);
  RS_ISSUE(oA0,oA1,oB0,oB1,oB2,oB3);
  WAITV(6);
  RS_DSW(0u, eA0,eA1,eB0,eB1,eB2,eB3);
  LGKM0; BAR;

  for (int t = 0; t < T; t += 2){
    if (t + 2 < T) RS_ISSUE(eA0,eA1,eB0,eB1,eB2,eB3);
    COMP(0u);
    if (t + 2 < T) WAITV(6); else WAITV(0);
    RS_DSW(RSBUF, oA0,oA1,oB0,oB1,oB2,oB3);
    LGKM0; BAR;
    if (t + 3 < T) RS_ISSUE(oA0,oA1,oB0,oB1,oB2,oB3);
    COMP(RSBUF);
    if (t + 2 < T){
      if (t + 3 < T) WAITV(6); else WAITV(0);
      RS_DSW(0u, eA0,eA1,eB0,eB1,eB2,eB3);
      LGKM0; BAR;
    }
  }

  __syncthreads();
  float* red = (float*)smem;
  if (wk == 1){
    #pragma unroll
    for (int n0 = 0; n0 < 8; ++n0)
      #pragma unroll
      for (int q = 0; q < 4; ++q){
        int row = wm*16 + ((lane>>4)<<2) + q;
        int col = n0*16 + (lane & 15);
        red[row*128 + col] = acc[n0][q];
      }
  }
  __syncthreads();
  if (wk == 0){
    #pragma unroll
    for (int n0 = 0; n0 < 8; ++n0)
      #pragma unroll
      for (int q = 0; q < 4; ++q){
        int row = wm*16 + ((lane>>4)<<2) + q;
        int col = n0*16 + (lane & 15);
        float v = (acc[n0][q] + red[row*128 + col]) * j.scale;
        size_t gp = (size_t)(m0 + row);
        if (j.mode == 1){
          float pe = j.add[gp*128 + col];
          float bb = j.bvec[col];
          v = pe / (1.f + __expf(-(v + bb)));
        } else if (j.add){
          v += j.add[gp*128 + col];
        }
        acc[n0][q] = v;
        if (j.outF) j.outF[gp*128 + col] = v;
      }
  }

  if (j.outT){
    __syncthreads();
    if (wk == 0){
      #pragma unroll
      for (int n0 = 0; n0 < 8; ++n0)
        #pragma unroll
        for (int q = 0; q < 4; ++q){
          int row = wm*16 + ((lane>>4)<<2) + q;
          int col = n0*16 + (lane & 15);
          red[row*128 + col] = acc[n0][q];
        }
    }
    __syncthreads();
    int col = tid & 127, seg = tid >> 7;
    unsigned wrds[8] __attribute__((aligned(16)));
    #pragma unroll
    for (int r = 0; r < 8; ++r){
      float v0 = red[(seg*16 + 2*r    )*128 + col];
      float v1 = red[(seg*16 + 2*r + 1)*128 + col];
      wrds[r] = cvt2(v0, v1);
    }
    bf16_t* dst = j.outT + (size_t)col * (size_t)j.outTstride + (m0 + seg*16);
    *(u32x4*)dst       = *(const u32x4*)&wrds[0];
    *((u32x4*)dst + 1) = *(const u32x4*)&wrds[4];
  }
}

// ================== gates GEMM (K=128) — round-1 verified ==================
#define GTBUF 24576

__global__ __launch_bounds__(256, 2) void gemm_gates(Job j0, Job j1, Job j2){
  __shared__ char smem[3*GTBUF];
  int bid = blockIdx.x;
  Job j = j0;
  if (bid >= j.nb){ bid -= j.nb; j = j1; if (bid >= j.nb){ bid -= j.nb; j = j2; } }
  const int K = j.K;
  const int T = K >> 6;
  const int m0 = bid << 5;
  const int tid = threadIdx.x;
  const int lane = tid & 63;
  const int wid = tid >> 6;
  const int wm = wid >> 1, wk = wid & 1;

  const char* Ab = (const char*)j.A;
  const char* Bb = (const char*)j.Bt;

  size_t a_src[2]; unsigned a_lds[2];
  #pragma unroll
  for (int i = 0; i < 2; ++i){
    int row = wid*8 + i*4 + (lane>>4);
    unsigned sb = (lane & 15) << 4;
    a_src[i] = (size_t)(m0 + row)*(size_t)K*4 + (size_t)(sb ^ ((row & 15) << 4));
    a_lds[i] = (unsigned)((wid*8 + i*4) * 256);
  }
  size_t b_src[4]; unsigned b_lds[4];
  #pragma unroll
  for (int i = 0; i < 4; ++i){
    int n  = wid*32 + i*8 + (lane>>3);
    unsigned sb = (lane & 7) << 4;
    b_src[i] = (size_t)n*(size_t)K*2 + (size_t)(sb ^ ((n & 7) << 4));
    b_lds[i] = (unsigned)(8192 + (wid*32 + i*8) * 128);
  }

  const int arow = wm*16 + (lane & 15);
  const unsigned acb  = (unsigned)(wk*128 + ((lane>>4) * 32));
  const unsigned aswz = (unsigned)((arow & 15) << 4);
  const unsigned a_rd0 = arow*256 + (acb ^ aswz);
  const unsigned a_rd1 = arow*256 + ((acb + 16) ^ aswz);
  unsigned b_rd[8];
  #pragma unroll
  for (int n0 = 0; n0 < 8; ++n0){
    int n = n0*16 + (lane & 15);
    unsigned c = (unsigned)(wk*64 + ((lane>>4) * 16));
    b_rd[n0] = 8192u + n*128 + (c ^ ((n & 7) << 4));
  }

  const f32x4 fzero = {0.f, 0.f, 0.f, 0.f};
  f32x4 acc[8];
  #pragma unroll
  for (int i = 0; i < 8; ++i) acc[i] = fzero;

  auto STAGE = [&](unsigned bufoff, int t){
    char* l = smem + bufoff;
    size_t ka = (size_t)t * 256;
    size_t kb = (size_t)t * 128;
    #pragma unroll
    for (int i = 0; i < 2; ++i) gload16(Ab + a_src[i] + ka, l + a_lds[i]);
    #pragma unroll
    for (int i = 0; i < 4; ++i) gload16(Bb + b_src[i] + kb, l + b_lds[i]);
  };

  STAGE(0, 0);
  if (T > 1){
    STAGE(GTBUF, 1);
    asm volatile("s_waitcnt vmcnt(6)" ::: "memory");
  } else {
    asm volatile("s_waitcnt vmcnt(0)" ::: "memory");
  }
  __builtin_amdgcn_s_barrier();

  for (int t = 0; t < T; ++t){
    char* l = smem + (unsigned)(t % 3) * GTBUF;
    if (t + 2 < T) STAGE((unsigned)((t+2) % 3) * GTBUF, t + 2);
    f32x4 a0 = *(const f32x4*)(l + a_rd0);
    f32x4 a1 = *(const f32x4*)(l + a_rd1);
    union { bf16x8 v; unsigned u[4]; } af;
    af.u[0] = cvt2(a0.x, a0.y);
    af.u[1] = cvt2(a0.z, a0.w);
    af.u[2] = cvt2(a1.x, a1.y);
    af.u[3] = cvt2(a1.z, a1.w);
    #pragma unroll
    for (int n0 = 0; n0 < 8; ++n0){
      bf16x8 bfr = *(const bf16x8*)(l + b_rd[n0]);
      acc[n0] = __builtin_amdgcn_mfma_f32_16x16x32_bf16(af.v, bfr, acc[n0], 0, 0, 0);
    }
    if (t + 1 < T){
      if (t + 2 < T) asm volatile("s_waitcnt vmcnt(6)" ::: "memory");
      else           asm volatile("s_waitcnt vmcnt(0)" ::: "memory");
      __builtin_amdgcn_s_barrier();
    }
  }

  __syncthreads();
  float* red = (float*)smem;
  if (wk == 1){
    #pragma unroll
    for (int n0 = 0; n0 < 8; ++n0)
      #pragma unroll
      for (int q = 0; q < 4; ++q){
        int row = wm*16 + ((lane>>4)<<2) + q;
        int col = n0*16 + (lane & 15);
        red[row*128 + col] = acc[n0][q];
      }
  }
  __syncthreads();
  if (wk == 0){
    #pragma unroll
    for (int n0 = 0; n0 < 8; ++n0)
      #pragma unroll
      for (int q = 0; q < 4; ++q){
        int row = wm*16 + ((lane>>4)<<2) + q;
        int col = n0*16 + (lane & 15);
        float v = (acc[n0][q] + red[row*128 + col]) * j.scale;
        size_t gp = (size_t)(m0 + row);
        if (j.mode == 1){
          float pe = j.add[gp*128 + col];
          float bb = j.bvec[col];
          v = pe / (1.f + __expf(-(v + bb)));
        } else if (j.add){
          v += j.add[gp*128 + col];
        }
        acc[n0][q] = v;
        if (j.outF) j.outF[gp*128 + col] = v;
      }
  }

  if (j.outT){
    __syncthreads();
    if (wk == 0){
      #pragma unroll
      for (int n0 = 0; n0 < 8; ++n0)
        #pragma unroll
        for (int q = 0; q < 4; ++q){
          int row = wm*16 + ((lane>>4)<<2) + q;
          int col = n0*16 + (lane & 15);
          red[row*128 + col] = acc[n0][q];
        }
    }
    __syncthreads();
    int col = tid & 127, seg = tid >> 7;
    unsigned wrds[8] __attribute__((aligned(16)));
    #pragma unroll
    for (int r = 0; r < 8; ++r){
      float v0 = red[(seg*16 + 2*r    )*128 + col];
      float v1 = red[(seg*16 + 2*r + 1)*128 + col];
      wrds[r] = cvt2(v0, v1);
    }
    bf16_t* dst = j.outT + (size_t)col * (size_t)j.outTstride + (m0 + seg*16);
    *(u32x4*)dst       = *(const u32x4*)&wrds[0];
    *((u32x4*)dst + 1) = *(const u32x4*)&wrds[4];
  }
}

// ---------------- gather GEMM (users), split-K=8, N=256 ----------------
#define GBUFB 40960

__global__ __launch_bounds__(256, 1) void gemm_gather(const float* __restrict__ Aup,
    const int* __restrict__ uidx, const bf16_t* __restrict__ B5t, float* __restrict__ partials){
  __shared__ char smem[3*GBUFB];
  const int bid = blockIdx.x;
  const int mtile = bid & 31, split = bid >> 5;
  const int tid = threadIdx.x, lane = tid & 63, wid = tid >> 6;
  const int wm = wid >> 1, wk = wid & 1;
  const int T = 16;
  const char* Ab = (const char*)Aup;
  const char* Bb = (const char*)B5t;

  size_t a_src[2]; unsigned a_lds[2];
  #pragma unroll
  for (int i = 0; i < 2; ++i){
    int row  = wid*8 + i*4 + (lane>>4);
    int grow = uidx[mtile*32 + row];
    unsigned sb = (lane & 15) << 4;
    a_src[i] = (size_t)grow*(size_t)(PP*4) + (size_t)((sb ^ ((row & 15) << 4)) + split*4096);
    a_lds[i] = (unsigned)((wid*8 + i*4) * 256);
  }
  size_t b_src[8]; unsigned b_lds[8];
  #pragma unroll
  for (int i = 0; i < 8; ++i){
    int n  = wid*64 + i*8 + (lane>>3);
    unsigned sb = (lane & 7) << 4;
    b_src[i] = (size_t)n*(size_t)(PP*2) + (size_t)((sb ^ ((n & 7) << 4)) + split*2048);
    b_lds[i] = (unsigned)(8192 + (wid*64 + i*8) * 128);
  }
  const int arow = wm*16 + (lane & 15);
  const unsigned acb  = (unsigned)(wk*128 + ((lane>>4)*32));
  const unsigned aswz = (unsigned)((arow & 15) << 4);
  const unsigned a_rd0 = arow*256 + (acb ^ aswz);
  const unsigned a_rd1 = arow*256 + ((acb + 16) ^ aswz);
  unsigned b_rd[16];
  #pragma unroll
  for (int n0 = 0; n0 < 16; ++n0){
    int n = n0*16 + (lane & 15);
    unsigned c = (unsigned)(wk*64 + ((lane>>4)*16));
    b_rd[n0] = 8192u + n*128 + (c ^ ((n & 7) << 4));
  }
  const f32x4 fzero = {0.f,0.f,0.f,0.f};
  f32x4 acc[16];
  #pragma unroll
  for (int i = 0; i < 16; ++i) acc[i] = fzero;

  auto STAGE = [&](unsigned bufoff, int t){
    char* l = smem + bufoff;
    size_t ka = (size_t)t*256, kb = (size_t)t*128;
    #pragma unroll
    for (int i = 0; i < 2; ++i) gload16(Ab + a_src[i] + ka, l + a_lds[i]);
    #pragma unroll
    for (int i = 0; i < 8; ++i) gload16(Bb + b_src[i] + kb, l + b_lds[i]);
  };
  STAGE(0, 0);
  STAGE(GBUFB, 1);
  asm volatile("s_waitcnt vmcnt(10)" ::: "memory");
  __builtin_amdgcn_s_barrier();
  for (int t = 0; t < T; ++t){
    char* l = smem + (unsigned)(t % 3) * GBUFB;
    if (t + 2 < T) STAGE((unsigned)((t+2)%3)*GBUFB, t+2);
    f32x4 a0 = *(const f32x4*)(l + a_rd0);
    f32x4 a1 = *(const f32x4*)(l + a_rd1);
    union { bf16x8 v; unsigned u[4]; } af;
    af.u[0] = cvt2(a0.x, a0.y);
    af.u[1] = cvt2(a0.z, a0.w);
    af.u[2] = cvt2(a1.x, a1.y);
    af.u[3] = cvt2(a1.z, a1.w);
    #pragma unroll
    for (int n0 = 0; n0 < 16; ++n0){
      bf16x8 bfr = *(const bf16x8*)(l + b_rd[n0]);
      acc[n0] = __builtin_amdgcn_mfma_f32_16x16x32_bf16(af.v, bfr, acc[n0], 0,0,0);
    }
    if (t + 1 < T){
      if (t + 2 < T) asm volatile("s_waitcnt vmcnt(10)" ::: "memory");
      else           asm volatile("s_waitcnt vmcnt(0)" ::: "memory");
      __builtin_amdgcn_s_barrier();
    }
  }
  __syncthreads();
  float* red = (float*)smem;
  if (wk == 1){
    #pragma unroll
    for (int n0 = 0; n0 < 16; ++n0)
      #pragma unroll
      for (int q = 0; q < 4; ++q){
        int row = wm*16 + ((lane>>4)<<2) + q;
        int col = n0*16 + (lane & 15);
        red[row*256 + col] = acc[n0][q];
      }
  }
  __syncthreads();
  if (wk == 0){
    #pragma unroll
    for (int n0 = 0; n0 < 16; ++n0)
      #pragma unroll
      for (int q = 0; q < 4; ++q){
        int row = wm*16 + ((lane>>4)<<2) + q;
        int col = n0*16 + (lane & 15);
        float v = acc[n0][q] + red[row*256 + col];
        partials[((size_t)split*1024 + mtile*32 + row)*256 + col] = v;
      }
  }
}

__global__ void prep_wt(const float* w0, const float* w1, const float* w2,
                        bf16_t* o0, bf16_t* o1, bf16_t* o2){
  const float* w = (blockIdx.x == 0) ? w0 : (blockIdx.x == 1) ? w1 : w2;
  bf16_t*      o = (blockIdx.x == 0) ? o0 : (blockIdx.x == 1) ? o1 : o2;
  int tid = threadIdx.x;
  int n = tid >> 1, h = tid & 1;
  unsigned wr[32] __attribute__((aligned(16)));
  #pragma unroll
  for (int r = 0; r < 32; ++r){
    float v0 = w[(h*64 + 2*r    )*128 + n];
    float v1 = w[(h*64 + 2*r + 1)*128 + n];
    wr[r] = cvt2(v0, v1);
  }
  u32x4* dst = (u32x4*)(o + n*128 + h*64);
  #pragma unroll
  for (int i = 0; i < 8; ++i) dst[i] = *(const u32x4*)&wr[i*4];
}

__global__ void reduce_users(const float* __restrict__ partials, float* __restrict__ out){
  int idx = blockIdx.x * 256 + threadIdx.x;
  int b = idx >> 8, n = idx & 255;
  float s = 0.f;
  #pragma unroll
  for (int k = 0; k < 8; ++k) s += partials[((size_t)k*1024 + b)*256 + n];
  if (n < 128) out[((size_t)(3*PP) + b)*128 + n]           = s;
  else         out[((size_t)(3*PP) + BB + b)*128 + (n-128)] = s;
}

extern "C" void kernel_launch(void* const* d_in, const int* in_sizes, int n_in,
                              void* d_out, int out_size, void* d_ws, size_t ws_size,
                              hipStream_t stream){
  const float* pe   = (const float*)d_in[0];
  const float* wgeo = (const float*)d_in[1];
  const float* bgeo = (const float*)d_in[2];
  const float* wseq = (const float*)d_in[3];
  const float* bseq = (const float*)d_in[4];
  const float* wcol = (const float*)d_in[5];
  const float* bcol = (const float*)d_in[6];
  const float* hup  = (const float*)d_in[7];
  const float* hpu  = (const float*)d_in[8];
  const float* hsrc = (const float*)d_in[9];
  const float* htar = (const float*)d_in[10];
  const float* geo  = (const float*)d_in[11];
  const int*   uidx = (const int*)d_in[12];
  float* out = (float*)d_out;

  char* w = (char*)d_ws;
  const size_t MB = 1024*1024;
  float*  x_f32 = (float*)(w);
  float*  g_f32 = (float*)(w + 4*MB);
  float*  s_f32 = (float*)(w + 8*MB);
  bf16_t* xT    = (bf16_t*)(w + 12*MB);
  bf16_t* gT    = (bf16_t*)(w + 14*MB);
  bf16_t* sT    = (bf16_t*)(w + 16*MB);
  bf16_t* upT   = (bf16_t*)(w + 18*MB);
  bf16_t* tarT  = (bf16_t*)(w + 19*MB);
  bf16_t* b5t   = (bf16_t*)(w + 20*MB);
  bf16_t* wtg   = (bf16_t*)(w + 24*MB);
  bf16_t* wts   = (bf16_t*)(w + 24*MB + 32768);
  bf16_t* wtc   = (bf16_t*)(w + 24*MB + 65536);
  float*  parts = (float*)(w + 25*MB);

  prep_wt<<<3, 256, 0, stream>>>(wgeo, wseq, wcol, wtg, wts, wtc);

  // gates: gate = pe * sigmoid(pe@W + b)
  Job jg{pe, wtg, pe, bgeo, g_f32, gT, PP, 1.f, 128, 256, 1};
  Job js{pe, wts, pe, bseq, s_f32, sT, PP, 1.f, 128, 256, 1};
  Job jc{pe, wtc, pe, bcol, x_f32, xT, PP, 1.f, 128, 256, 1};
  gemm_gates<<<768, 256, 0, stream>>>(jg, js, jc);

  // phase B (slab kernel, 16-row tiles): tmp_up = HG_up@x ; geo_pois = g + 0.4*(geo@g) ;
  // tmp_tar = HG_poi_tar@s
  Job j1 {hup,  xT, nullptr, nullptr, nullptr,               upT,                  UU, 1.f,  PP, 256, 0};
  Job j3 {geo,  gT, g_f32,   nullptr, out + (size_t)PP*128,  b5t + (size_t)128*PP, PP, 0.4f, PP, 512, 0};
  Job j4a{htar, sT, nullptr, nullptr, nullptr,               tarT,                 EE, 1.f,  PP, 256, 0};
  gemm_slab<<<1024, 512, 0, stream>>>(j1, j3, j4a);

  // phase C (reg-staged, 32-row tiles): hg_pois = x + HG_pu@tmp_up ; trans_pois = s + src@tmp_tar
  Job j2 {hpu,  upT,  x_f32, nullptr, out,                     b5t,     PP, 1.f, UU, 256, 0};
  Job j4b{hsrc, tarT, s_f32, nullptr, out + (size_t)2*PP*128,  nullptr, 0,  1.f, EE, 256, 0};
  Job jd = j4b; jd.nb = 0;
  gemm_rs<<<512, 256, 0, stream>>>(j2, j4b, jd);

  // users: HG_up[user_idx] @ [hg_pois | geo_pois], split-K=8 then deterministic reduce
  gemm_gather<<<256, 256, 0, stream>>>(hup, uidx, b5t, parts);
  reduce_users<<<1024, 256, 0, stream>>>(parts, out);
}

// Round 10
// 315.327 us; speedup vs baseline: 1.4860x; 1.4860x over previous
//
#include <hip/hip_runtime.h>
#include <hip/hip_bf16.h>

#define PP 8192
#define UU 4096
#define EE 4096
#define BB 1024

using f32x4  = __attribute__((ext_vector_type(4))) float;
using u32x4  = __attribute__((ext_vector_type(4))) unsigned int;
using bf16x8 = __attribute__((ext_vector_type(8))) short;
typedef __hip_bfloat16 bf16_t;

__device__ __forceinline__ unsigned cvt2(float a, float b){
  unsigned r;
  asm("v_cvt_pk_bf16_f32 %0, %1, %2" : "=v"(r) : "v"(a), "v"(b));
  return r;
}

__device__ __forceinline__ void gload16(const void* g, void* l){
  __builtin_amdgcn_global_load_lds((const __attribute__((address_space(1))) void*)g,
                                   (__attribute__((address_space(3))) void*)l, 16, 0, 0);
}

struct Job {
  const float*  A;      // [M][K] f32
  const bf16_t* Bt;     // [128][K] bf16 (B transposed)
  const float*  add;    // epilogue add (or pe for sigmoid mode); may be null
  const float*  bvec;   // sigmoid bias [128]; null otherwise
  float*        outF;   // f32 out [M][128]; may be null
  bf16_t*       outT;   // transposed bf16 out [128][stride]; may be null
  int           outTstride;
  float         scale;  // final = add + scale*C  (mode 0)
  int           K;
  int           nb;     // number of 32-row blocks
  int           mode;   // 0 linear, 1 sigmoid-gate
};

#define WAITV(n) asm volatile("s_waitcnt vmcnt(" #n ")" ::: "memory")
#define LGKM0    asm volatile("s_waitcnt lgkmcnt(0)" ::: "memory")
#define SBAR     __builtin_amdgcn_sched_barrier(0)
#define BAR      __builtin_amdgcn_s_barrier()

#define RSBUF 24576

// ============ gemm_rs2 (phase B): dual 16KB-offset k-windows per step ============
// Identical to gemm_rs except each K-step stages window0 (k = t*32) AND
// window1 (k = K/2 + t*32) concurrently -> simultaneous reads cover both
// bit-14 address residues. LDS image / frags / epilogue byte-identical.
__global__ __launch_bounds__(256, 2) void gemm_rs2(Job j0, Job j1, Job j2){
  __shared__ char smem[2*RSBUF];
  int bid = blockIdx.x;
  Job j = j0;
  if (bid >= j.nb){ bid -= j.nb; j = j1; if (bid >= j.nb){ bid -= j.nb; j = j2; } }
  const int K = j.K;
  const int T = K >> 6;                 // steps; each covers 32k from EACH half
  const int m0 = bid << 5;
  const int tid = threadIdx.x;
  const int lane = tid & 63;
  const int wid = tid >> 6;
  const int wm = wid >> 1, wk = wid & 1;   // wk now selects k-half window

  // ---- staging source pointers ----
  const int srow = tid >> 3;            // 0..31
  const int scol = (tid & 7) * 16;      // LDS byte within the 128B row-chunk
  const size_t khalfA = (size_t)K * 2;  // (K/2) f32 = K*2 bytes
  const size_t khalfB = (size_t)K;      // (K/2) bf16 = K bytes
  // A: window0 at +0, window1 at +khalfA (odd multiple of 16KB when K=8192)
  const char* ap0 = (const char*)j.A + (size_t)(m0 + srow)*(size_t)K*4 + (unsigned)scol;
  const char* ap1 = ap0 + khalfA;
  // B: thread's 16B goes to LDS byte scol of the row; window = scol>=64
  const int bwin = (tid & 7) >> 2;            // 0 or 1
  const unsigned bin = (unsigned)(((tid & 7) & 3) * 16);  // byte within window
  const char* bq0 = (const char*)j.Bt + (size_t)(srow      )*(size_t)K*2 + (size_t)bwin*khalfB + bin;
  const char* bq1 = (const char*)j.Bt + (size_t)(srow +  32)*(size_t)K*2 + (size_t)bwin*khalfB + bin;
  const char* bq2 = (const char*)j.Bt + (size_t)(srow +  64)*(size_t)K*2 + (size_t)bwin*khalfB + bin;
  const char* bq3 = (const char*)j.Bt + (size_t)(srow +  96)*(size_t)K*2 + (size_t)bwin*khalfB + bin;

  // ---- LDS write addresses (identical image to gemm_rs) ----
  const unsigned aswzw = (unsigned)((srow & 15) << 4);
  const unsigned wa0 = (unsigned)(srow*256) + ((unsigned)scol ^ aswzw);
  const unsigned wa1 = (unsigned)(srow*256) + (((unsigned)scol + 128u) ^ aswzw);
  const unsigned bswzw = (unsigned)((srow & 7) << 4);
  const unsigned wb0 = 8192u + (unsigned)(srow*128) + ((unsigned)scol ^ bswzw);

  // ---- fragment read addresses (identical) ----
  const int arow = wm*16 + (lane & 15);
  const unsigned acb  = (unsigned)(wk*128 + ((lane>>4) * 32));
  const unsigned aswz = (unsigned)((arow & 15) << 4);
  const unsigned a_rd0 = arow*256 + (acb ^ aswz);
  const unsigned a_rd1 = arow*256 + ((acb + 16) ^ aswz);
  unsigned b_rd[8];
  #pragma unroll
  for (int n0 = 0; n0 < 8; ++n0){
    int n = n0*16 + (lane & 15);
    unsigned c = (unsigned)(wk*64 + ((lane>>4) * 16));
    b_rd[n0] = 8192u + n*128 + (c ^ ((n & 7) << 4));
  }

  f32x4 acc[8];
  const f32x4 fzero = {0.f,0.f,0.f,0.f};
  #pragma unroll
  for (int i = 0; i < 8; ++i) acc[i] = fzero;

  f32x4 eA0,eA1,eB0,eB1,eB2,eB3, oA0,oA1,oB0,oB1,oB2,oB3;

#define RS2_ISSUE(A0,A1,B0,B1,B2,B3) do { \
    asm volatile("global_load_dwordx4 %0, %1, off" : "=&v"(A0) : "v"(ap0) : "memory"); \
    asm volatile("global_load_dwordx4 %0, %1, off" : "=&v"(A1) : "v"(ap1) : "memory"); \
    asm volatile("global_load_dwordx4 %0, %1, off" : "=&v"(B0) : "v"(bq0) : "memory"); \
    asm volatile("global_load_dwordx4 %0, %1, off" : "=&v"(B1) : "v"(bq1) : "memory"); \
    asm volatile("global_load_dwordx4 %0, %1, off" : "=&v"(B2) : "v"(bq2) : "memory"); \
    asm volatile("global_load_dwordx4 %0, %1, off" : "=&v"(B3) : "v"(bq3) : "memory"); \
    ap0 += 128; ap1 += 128; bq0 += 64; bq1 += 64; bq2 += 64; bq3 += 64; } while(0)

#define RS2_DSW(bo,A0,A1,B0,B1,B2,B3) do { \
    asm volatile("ds_write_b128 %0, %1" :: "v"((bo) + wa0), "v"(A0) : "memory"); \
    asm volatile("ds_write_b128 %0, %1" :: "v"((bo) + wa1), "v"(A1) : "memory"); \
    asm volatile("ds_write_b128 %0, %1"              :: "v"((bo) + wb0), "v"(B0) : "memory"); \
    asm volatile("ds_write_b128 %0, %1 offset:4096"  :: "v"((bo) + wb0), "v"(B1) : "memory"); \
    asm volatile("ds_write_b128 %0, %1 offset:8192"  :: "v"((bo) + wb0), "v"(B2) : "memory"); \
    asm volatile("ds_write_b128 %0, %1 offset:12288" :: "v"((bo) + wb0), "v"(B3) : "memory"); } while(0)

  auto COMP = [&](unsigned bo){
    f32x4 a0, a1;
    asm volatile("ds_read_b128 %0, %1" : "=v"(a0) : "v"(bo + a_rd0));
    asm volatile("ds_read_b128 %0, %1" : "=v"(a1) : "v"(bo + a_rd1));
    bf16x8 b0,b1,b2,b3,b4,b5,b6,b7;
    asm volatile("ds_read_b128 %0, %1" : "=v"(b0) : "v"(bo + b_rd[0]));
    asm volatile("ds_read_b128 %0, %1" : "=v"(b1) : "v"(bo + b_rd[1]));
    asm volatile("ds_read_b128 %0, %1" : "=v"(b2) : "v"(bo + b_rd[2]));
    asm volatile("ds_read_b128 %0, %1" : "=v"(b3) : "v"(bo + b_rd[3]));
    asm volatile("ds_read_b128 %0, %1" : "=v"(b4) : "v"(bo + b_rd[4]));
    asm volatile("ds_read_b128 %0, %1" : "=v"(b5) : "v"(bo + b_rd[5]));
    asm volatile("ds_read_b128 %0, %1" : "=v"(b6) : "v"(bo + b_rd[6]));
    asm volatile("ds_read_b128 %0, %1" : "=v"(b7) : "v"(bo + b_rd[7]));
    LGKM0;
    SBAR;
    union { bf16x8 v; unsigned u[4]; } af;
    af.u[0] = cvt2(a0.x, a0.y);
    af.u[1] = cvt2(a0.z, a0.w);
    af.u[2] = cvt2(a1.x, a1.y);
    af.u[3] = cvt2(a1.z, a1.w);
    acc[0] = __builtin_amdgcn_mfma_f32_16x16x32_bf16(af.v, b0, acc[0], 0,0,0);
    acc[1] = __builtin_amdgcn_mfma_f32_16x16x32_bf16(af.v, b1, acc[1], 0,0,0);
    acc[2] = __builtin_amdgcn_mfma_f32_16x16x32_bf16(af.v, b2, acc[2], 0,0,0);
    acc[3] = __builtin_amdgcn_mfma_f32_16x16x32_bf16(af.v, b3, acc[3], 0,0,0);
    acc[4] = __builtin_amdgcn_mfma_f32_16x16x32_bf16(af.v, b4, acc[4], 0,0,0);
    acc[5] = __builtin_amdgcn_mfma_f32_16x16x32_bf16(af.v, b5, acc[5], 0,0,0);
    acc[6] = __builtin_amdgcn_mfma_f32_16x16x32_bf16(af.v, b6, acc[6], 0,0,0);
    acc[7] = __builtin_amdgcn_mfma_f32_16x16x32_bf16(af.v, b7, acc[7], 0,0,0);
  };

  RS2_ISSUE(eA0,eA1,eB0,eB1,eB2,eB3);
  RS2_ISSUE(oA0,oA1,oB0,oB1,oB2,oB3);
  WAITV(6);
  RS2_DSW(0u, eA0,eA1,eB0,eB1,eB2,eB3);
  LGKM0; BAR;

  for (int t = 0; t < T; t += 2){
    if (t + 2 < T) RS2_ISSUE(eA0,eA1,eB0,eB1,eB2,eB3);
    COMP(0u);
    if (t + 2 < T) WAITV(6); else WAITV(0);
    RS2_DSW(RSBUF, oA0,oA1,oB0,oB1,oB2,oB3);
    LGKM0; BAR;
    if (t + 3 < T) RS2_ISSUE(oA0,oA1,oB0,oB1,oB2,oB3);
    COMP(RSBUF);
    if (t + 2 < T){
      if (t + 3 < T) WAITV(6); else WAITV(0);
      RS2_DSW(0u, eA0,eA1,eB0,eB1,eB2,eB3);
      LGKM0; BAR;
    }
  }
#undef RS2_ISSUE
#undef RS2_DSW

  // ---- K-split (wk) reduction + epilogue (identical to gemm_rs) ----
  __syncthreads();
  float* red = (float*)smem;
  if (wk == 1){
    #pragma unroll
    for (int n0 = 0; n0 < 8; ++n0)
      #pragma unroll
      for (int q = 0; q < 4; ++q){
        int row = wm*16 + ((lane>>4)<<2) + q;
        int col = n0*16 + (lane & 15);
        red[row*128 + col] = acc[n0][q];
      }
  }
  __syncthreads();
  if (wk == 0){
    #pragma unroll
    for (int n0 = 0; n0 < 8; ++n0)
      #pragma unroll
      for (int q = 0; q < 4; ++q){
        int row = wm*16 + ((lane>>4)<<2) + q;
        int col = n0*16 + (lane & 15);
        float v = (acc[n0][q] + red[row*128 + col]) * j.scale;
        size_t gp = (size_t)(m0 + row);
        if (j.mode == 1){
          float pe = j.add[gp*128 + col];
          float bb = j.bvec[col];
          v = pe / (1.f + __expf(-(v + bb)));
        } else if (j.add){
          v += j.add[gp*128 + col];
        }
        acc[n0][q] = v;
        if (j.outF) j.outF[gp*128 + col] = v;
      }
  }

  if (j.outT){
    __syncthreads();
    if (wk == 0){
      #pragma unroll
      for (int n0 = 0; n0 < 8; ++n0)
        #pragma unroll
        for (int q = 0; q < 4; ++q){
          int row = wm*16 + ((lane>>4)<<2) + q;
          int col = n0*16 + (lane & 15);
          red[row*128 + col] = acc[n0][q];
        }
    }
    __syncthreads();
    int col = tid & 127, seg = tid >> 7;
    unsigned wrds[8] __attribute__((aligned(16)));
    #pragma unroll
    for (int r = 0; r < 8; ++r){
      float v0 = red[(seg*16 + 2*r    )*128 + col];
      float v1 = red[(seg*16 + 2*r + 1)*128 + col];
      wrds[r] = cvt2(v0, v1);
    }
    bf16_t* dst = j.outT + (size_t)col * (size_t)j.outTstride + (m0 + seg*16);
    *(u32x4*)dst       = *(const u32x4*)&wrds[0];
    *((u32x4*)dst + 1) = *(const u32x4*)&wrds[4];
  }
}

// ============ gemm_rs (phase C) — round-8 verified, unchanged ============
__global__ __launch_bounds__(256, 2) void gemm_rs(Job j0, Job j1, Job j2){
  __shared__ char smem[2*RSBUF];
  int bid = blockIdx.x;
  Job j = j0;
  if (bid >= j.nb){ bid -= j.nb; j = j1; if (bid >= j.nb){ bid -= j.nb; j = j2; } }
  const int K = j.K;
  const int T = K >> 6;
  const int m0 = bid << 5;
  const int tid = threadIdx.x;
  const int lane = tid & 63;
  const int wid = tid >> 6;
  const int wm = wid >> 1, wk = wid & 1;

  const int srow = tid >> 3;
  const int scol = (tid & 7) * 16;
  const char* ap  = (const char*)j.A  + (size_t)(m0 + srow)*(size_t)K*4 + (unsigned)scol;
  const char* bq0 = (const char*)j.Bt + (size_t)(srow      )*(size_t)K*2 + (unsigned)scol;
  const char* bq1 = (const char*)j.Bt + (size_t)(srow +  32)*(size_t)K*2 + (unsigned)scol;
  const char* bq2 = (const char*)j.Bt + (size_t)(srow +  64)*(size_t)K*2 + (unsigned)scol;
  const char* bq3 = (const char*)j.Bt + (size_t)(srow +  96)*(size_t)K*2 + (unsigned)scol;

  const unsigned aswzw = (unsigned)((srow & 15) << 4);
  const unsigned wa0 = (unsigned)(srow*256) + ((unsigned)scol ^ aswzw);
  const unsigned wa1 = (unsigned)(srow*256) + (((unsigned)scol + 128u) ^ aswzw);
  const unsigned bswzw = (unsigned)((srow & 7) << 4);
  const unsigned wb0 = 8192u + (unsigned)(srow*128) + ((unsigned)scol ^ bswzw);

  const int arow = wm*16 + (lane & 15);
  const unsigned acb  = (unsigned)(wk*128 + ((lane>>4) * 32));
  const unsigned aswz = (unsigned)((arow & 15) << 4);
  const unsigned a_rd0 = arow*256 + (acb ^ aswz);
  const unsigned a_rd1 = arow*256 + ((acb + 16) ^ aswz);
  unsigned b_rd[8];
  #pragma unroll
  for (int n0 = 0; n0 < 8; ++n0){
    int n = n0*16 + (lane & 15);
    unsigned c = (unsigned)(wk*64 + ((lane>>4) * 16));
    b_rd[n0] = 8192u + n*128 + (c ^ ((n & 7) << 4));
  }

  f32x4 acc[8];
  const f32x4 fzero = {0.f,0.f,0.f,0.f};
  #pragma unroll
  for (int i = 0; i < 8; ++i) acc[i] = fzero;

  f32x4 eA0,eA1,eB0,eB1,eB2,eB3, oA0,oA1,oB0,oB1,oB2,oB3;

#define RS_ISSUE(A0,A1,B0,B1,B2,B3) do { \
    asm volatile("global_load_dwordx4 %0, %2, off\n\t" \
                 "global_load_dwordx4 %1, %2, off offset:128" \
      : "=&v"(A0), "=&v"(A1) : "v"(ap) : "memory"); \
    asm volatile("global_load_dwordx4 %0, %1, off" : "=&v"(B0) : "v"(bq0) : "memory"); \
    asm volatile("global_load_dwordx4 %0, %1, off" : "=&v"(B1) : "v"(bq1) : "memory"); \
    asm volatile("global_load_dwordx4 %0, %1, off" : "=&v"(B2) : "v"(bq2) : "memory"); \
    asm volatile("global_load_dwordx4 %0, %1, off" : "=&v"(B3) : "v"(bq3) : "memory"); \
    ap += 256; bq0 += 128; bq1 += 128; bq2 += 128; bq3 += 128; } while(0)

#define RS_DSW(bo,A0,A1,B0,B1,B2,B3) do { \
    asm volatile("ds_write_b128 %0, %1" :: "v"((bo) + wa0), "v"(A0) : "memory"); \
    asm volatile("ds_write_b128 %0, %1" :: "v"((bo) + wa1), "v"(A1) : "memory"); \
    asm volatile("ds_write_b128 %0, %1"              :: "v"((bo) + wb0), "v"(B0) : "memory"); \
    asm volatile("ds_write_b128 %0, %1 offset:4096"  :: "v"((bo) + wb0), "v"(B1) : "memory"); \
    asm volatile("ds_write_b128 %0, %1 offset:8192"  :: "v"((bo) + wb0), "v"(B2) : "memory"); \
    asm volatile("ds_write_b128 %0, %1 offset:12288" :: "v"((bo) + wb0), "v"(B3) : "memory"); } while(0)

  auto COMP = [&](unsigned bo){
    f32x4 a0, a1;
    asm volatile("ds_read_b128 %0, %1" : "=v"(a0) : "v"(bo + a_rd0));
    asm volatile("ds_read_b128 %0, %1" : "=v"(a1) : "v"(bo + a_rd1));
    bf16x8 b0,b1,b2,b3,b4,b5,b6,b7;
    asm volatile("ds_read_b128 %0, %1" : "=v"(b0) : "v"(bo + b_rd[0]));
    asm volatile("ds_read_b128 %0, %1" : "=v"(b1) : "v"(bo + b_rd[1]));
    asm volatile("ds_read_b128 %0, %1" : "=v"(b2) : "v"(bo + b_rd[2]));
    asm volatile("ds_read_b128 %0, %1" : "=v"(b3) : "v"(bo + b_rd[3]));
    asm volatile("ds_read_b128 %0, %1" : "=v"(b4) : "v"(bo + b_rd[4]));
    asm volatile("ds_read_b128 %0, %1" : "=v"(b5) : "v"(bo + b_rd[5]));
    asm volatile("ds_read_b128 %0, %1" : "=v"(b6) : "v"(bo + b_rd[6]));
    asm volatile("ds_read_b128 %0, %1" : "=v"(b7) : "v"(bo + b_rd[7]));
    LGKM0;
    SBAR;
    union { bf16x8 v; unsigned u[4]; } af;
    af.u[0] = cvt2(a0.x, a0.y);
    af.u[1] = cvt2(a0.z, a0.w);
    af.u[2] = cvt2(a1.x, a1.y);
    af.u[3] = cvt2(a1.z, a1.w);
    acc[0] = __builtin_amdgcn_mfma_f32_16x16x32_bf16(af.v, b0, acc[0], 0,0,0);
    acc[1] = __builtin_amdgcn_mfma_f32_16x16x32_bf16(af.v, b1, acc[1], 0,0,0);
    acc[2] = __builtin_amdgcn_mfma_f32_16x16x32_bf16(af.v, b2, acc[2], 0,0,0);
    acc[3] = __builtin_amdgcn_mfma_f32_16x16x32_bf16(af.v, b3, acc[3], 0,0,0);
    acc[4] = __builtin_amdgcn_mfma_f32_16x16x32_bf16(af.v, b4, acc[4], 0,0,0);
    acc[5] = __builtin_amdgcn_mfma_f32_16x16x32_bf16(af.v, b5, acc[5], 0,0,0);
    acc[6] = __builtin_amdgcn_mfma_f32_16x16x32_bf16(af.v, b6, acc[6], 0,0,0);
    acc[7] = __builtin_amdgcn_mfma_f32_16x16x32_bf16(af.v, b7, acc[7], 0,0,0);
  };

  RS_ISSUE(eA0,eA1,eB0,eB1,eB2,eB3);
  RS_ISSUE(oA0,oA1,oB0,oB1,oB2,oB3);
  WAITV(6);
  RS_DSW(0u, eA0,eA1,eB0,eB1,eB2,eB3);
  LGKM0; BAR;

  for (int t = 0; t < T; t += 2){
    if (t + 2 < T) RS_ISSUE(eA0,eA1,eB0,eB1,eB2,eB3);
    COMP(0u);
    if (t + 2 < T) WAITV(6); else WAITV(0);
    RS_DSW(RSBUF, oA0,oA1,oB0,oB1,oB2,oB3);
    LGKM0; BAR;
    if (t + 3 < T) RS_ISSUE(oA0,oA1,oB0,oB1,oB2,oB3);
    COMP(RSBUF);
    if (t + 2 < T){
      if (t + 3 < T) WAITV(6); else WAITV(0);
      RS_DSW(0u, eA0,eA1,eB0,eB1,eB2,eB3);
      LGKM0; BAR;
    }
  }
#undef RS_ISSUE
#undef RS_DSW

  __syncthreads();
  float* red = (float*)smem;
  if (wk == 1){
    #pragma unroll
    for (int n0 = 0; n0 < 8; ++n0)
      #pragma unroll
      for (int q = 0; q < 4; ++q){
        int row = wm*16 + ((lane>>4)<<2) + q;
        int col = n0*16 + (lane & 15);
        red[row*128 + col] = acc[n0][q];
      }
  }
  __syncthreads();
  if (wk == 0){
    #pragma unroll
    for (int n0 = 0; n0 < 8; ++n0)
      #pragma unroll
      for (int q = 0; q < 4; ++q){
        int row = wm*16 + ((lane>>4)<<2) + q;
        int col = n0*16 + (lane & 15);
        float v = (acc[n0][q] + red[row*128 + col]) * j.scale;
        size_t gp = (size_t)(m0 + row);
        if (j.mode == 1){
          float pe = j.add[gp*128 + col];
          float bb = j.bvec[col];
          v = pe / (1.f + __expf(-(v + bb)));
        } else if (j.add){
          v += j.add[gp*128 + col];
        }
        acc[n0][q] = v;
        if (j.outF) j.outF[gp*128 + col] = v;
      }
  }

  if (j.outT){
    __syncthreads();
    if (wk == 0){
      #pragma unroll
      for (int n0 = 0; n0 < 8; ++n0)
        #pragma unroll
        for (int q = 0; q < 4; ++q){
          int row = wm*16 + ((lane>>4)<<2) + q;
          int col = n0*16 + (lane & 15);
          red[row*128 + col] = acc[n0][q];
        }
    }
    __syncthreads();
    int col = tid & 127, seg = tid >> 7;
    unsigned wrds[8] __attribute__((aligned(16)));
    #pragma unroll
    for (int r = 0; r < 8; ++r){
      float v0 = red[(seg*16 + 2*r    )*128 + col];
      float v1 = red[(seg*16 + 2*r + 1)*128 + col];
      wrds[r] = cvt2(v0, v1);
    }
    bf16_t* dst = j.outT + (size_t)col * (size_t)j.outTstride + (m0 + seg*16);
    *(u32x4*)dst       = *(const u32x4*)&wrds[0];
    *((u32x4*)dst + 1) = *(const u32x4*)&wrds[4];
  }
}

// ================== gates GEMM (K=128) — round-1 verified ==================
#define GTBUF 24576

__global__ __launch_bounds__(256, 2) void gemm_gates(Job j0, Job j1, Job j2){
  __shared__ char smem[3*GTBUF];
  int bid = blockIdx.x;
  Job j = j0;
  if (bid >= j.nb){ bid -= j.nb; j = j1; if (bid >= j.nb){ bid -= j.nb; j = j2; } }
  const int K = j.K;
  const int T = K >> 6;
  const int m0 = bid << 5;
  const int tid = threadIdx.x;
  const int lane = tid & 63;
  const int wid = tid >> 6;
  const int wm = wid >> 1, wk = wid & 1;

  const char* Ab = (const char*)j.A;
  const char* Bb = (const char*)j.Bt;

  size_t a_src[2]; unsigned a_lds[2];
  #pragma unroll
  for (int i = 0; i < 2; ++i){
    int row = wid*8 + i*4 + (lane>>4);
    unsigned sb = (lane & 15) << 4;
    a_src[i] = (size_t)(m0 + row)*(size_t)K*4 + (size_t)(sb ^ ((row & 15) << 4));
    a_lds[i] = (unsigned)((wid*8 + i*4) * 256);
  }
  size_t b_src[4]; unsigned b_lds[4];
  #pragma unroll
  for (int i = 0; i < 4; ++i){
    int n  = wid*32 + i*8 + (lane>>3);
    unsigned sb = (lane & 7) << 4;
    b_src[i] = (size_t)n*(size_t)K*2 + (size_t)(sb ^ ((n & 7) << 4));
    b_lds[i] = (unsigned)(8192 + (wid*32 + i*8) * 128);
  }

  const int arow = wm*16 + (lane & 15);
  const unsigned acb  = (unsigned)(wk*128 + ((lane>>4) * 32));
  const unsigned aswz = (unsigned)((arow & 15) << 4);
  const unsigned a_rd0 = arow*256 + (acb ^ aswz);
  const unsigned a_rd1 = arow*256 + ((acb + 16) ^ aswz);
  unsigned b_rd[8];
  #pragma unroll
  for (int n0 = 0; n0 < 8; ++n0){
    int n = n0*16 + (lane & 15);
    unsigned c = (unsigned)(wk*64 + ((lane>>4) * 16));
    b_rd[n0] = 8192u + n*128 + (c ^ ((n & 7) << 4));
  }

  const f32x4 fzero = {0.f, 0.f, 0.f, 0.f};
  f32x4 acc[8];
  #pragma unroll
  for (int i = 0; i < 8; ++i) acc[i] = fzero;

  auto STAGE = [&](unsigned bufoff, int t){
    char* l = smem + bufoff;
    size_t ka = (size_t)t * 256;
    size_t kb = (size_t)t * 128;
    #pragma unroll
    for (int i = 0; i < 2; ++i) gload16(Ab + a_src[i] + ka, l + a_lds[i]);
    #pragma unroll
    for (int i = 0; i < 4; ++i) gload16(Bb + b_src[i] + kb, l + b_lds[i]);
  };

  STAGE(0, 0);
  if (T > 1){
    STAGE(GTBUF, 1);
    asm volatile("s_waitcnt vmcnt(6)" ::: "memory");
  } else {
    asm volatile("s_waitcnt vmcnt(0)" ::: "memory");
  }
  __builtin_amdgcn_s_barrier();

  for (int t = 0; t < T; ++t){
    char* l = smem + (unsigned)(t % 3) * GTBUF;
    if (t + 2 < T) STAGE((unsigned)((t+2) % 3) * GTBUF, t + 2);
    f32x4 a0 = *(const f32x4*)(l + a_rd0);
    f32x4 a1 = *(const f32x4*)(l + a_rd1);
    union { bf16x8 v; unsigned u[4]; } af;
    af.u[0] = cvt2(a0.x, a0.y);
    af.u[1] = cvt2(a0.z, a0.w);
    af.u[2] = cvt2(a1.x, a1.y);
    af.u[3] = cvt2(a1.z, a1.w);
    #pragma unroll
    for (int n0 = 0; n0 < 8; ++n0){
      bf16x8 bfr = *(const bf16x8*)(l + b_rd[n0]);
      acc[n0] = __builtin_amdgcn_mfma_f32_16x16x32_bf16(af.v, bfr, acc[n0], 0, 0, 0);
    }
    if (t + 1 < T){
      if (t + 2 < T) asm volatile("s_waitcnt vmcnt(6)" ::: "memory");
      else           asm volatile("s_waitcnt vmcnt(0)" ::: "memory");
      __builtin_amdgcn_s_barrier();
    }
  }

  __syncthreads();
  float* red = (float*)smem;
  if (wk == 1){
    #pragma unroll
    for (int n0 = 0; n0 < 8; ++n0)
      #pragma unroll
      for (int q = 0; q < 4; ++q){
        int row = wm*16 + ((lane>>4)<<2) + q;
        int col = n0*16 + (lane & 15);
        red[row*128 + col] = acc[n0][q];
      }
  }
  __syncthreads();
  if (wk == 0){
    #pragma unroll
    for (int n0 = 0; n0 < 8; ++n0)
      #pragma unroll
      for (int q = 0; q < 4; ++q){
        int row = wm*16 + ((lane>>4)<<2) + q;
        int col = n0*16 + (lane & 15);
        float v = (acc[n0][q] + red[row*128 + col]) * j.scale;
        size_t gp = (size_t)(m0 + row);
        if (j.mode == 1){
          float pe = j.add[gp*128 + col];
          float bb = j.bvec[col];
          v = pe / (1.f + __expf(-(v + bb)));
        } else if (j.add){
          v += j.add[gp*128 + col];
        }
        acc[n0][q] = v;
        if (j.outF) j.outF[gp*128 + col] = v;
      }
  }

  if (j.outT){
    __syncthreads();
    if (wk == 0){
      #pragma unroll
      for (int n0 = 0; n0 < 8; ++n0)
        #pragma unroll
        for (int q = 0; q < 4; ++q){
          int row = wm*16 + ((lane>>4)<<2) + q;
          int col = n0*16 + (lane & 15);
          red[row*128 + col] = acc[n0][q];
        }
    }
    __syncthreads();
    int col = tid & 127, seg = tid >> 7;
    unsigned wrds[8] __attribute__((aligned(16)));
    #pragma unroll
    for (int r = 0; r < 8; ++r){
      float v0 = red[(seg*16 + 2*r    )*128 + col];
      float v1 = red[(seg*16 + 2*r + 1)*128 + col];
      wrds[r] = cvt2(v0, v1);
    }
    bf16_t* dst = j.outT + (size_t)col * (size_t)j.outTstride + (m0 + seg*16);
    *(u32x4*)dst       = *(const u32x4*)&wrds[0];
    *((u32x4*)dst + 1) = *(const u32x4*)&wrds[4];
  }
}

// ---------------- gather GEMM (users), split-K=8, N=256 ----------------
#define GBUFB 40960

__global__ __launch_bounds__(256, 1) void gemm_gather(const float* __restrict__ Aup,
    const int* __restrict__ uidx, const bf16_t* __restrict__ B5t, float* __restrict__ partials){
  __shared__ char smem[3*GBUFB];
  const int bid = blockIdx.x;
  const int mtile = bid & 31, split = bid >> 5;
  const int tid = threadIdx.x, lane = tid & 63, wid = tid >> 6;
  const int wm = wid >> 1, wk = wid & 1;
  const int T = 16;
  const char* Ab = (const char*)Aup;
  const char* Bb = (const char*)B5t;

  size_t a_src[2]; unsigned a_lds[2];
  #pragma unroll
  for (int i = 0; i < 2; ++i){
    int row  = wid*8 + i*4 + (lane>>4);
    int grow = uidx[mtile*32 + row];
    unsigned sb = (lane & 15) << 4;
    a_src[i] = (size_t)grow*(size_t)(PP*4) + (size_t)((sb ^ ((row & 15) << 4)) + split*4096);
    a_lds[i] = (unsigned)((wid*8 + i*4) * 256);
  }
  size_t b_src[8]; unsigned b_lds[8];
  #pragma unroll
  for (int i = 0; i < 8; ++i){
    int n  = wid*64 + i*8 + (lane>>3);
    unsigned sb = (lane & 7) << 4;
    b_src[i] = (size_t)n*(size_t)(PP*2) + (size_t)((sb ^ ((n & 7) << 4)) + split*2048);
    b_lds[i] = (unsigned)(8192 + (wid*64 + i*8) * 128);
  }
  const int arow = wm*16 + (lane & 15);
  const unsigned acb  = (unsigned)(wk*128 + ((lane>>4)*32));
  const unsigned aswz = (unsigned)((arow & 15) << 4);
  const unsigned a_rd0 = arow*256 + (acb ^ aswz);
  const unsigned a_rd1 = arow*256 + ((acb + 16) ^ aswz);
  unsigned b_rd[16];
  #pragma unroll
  for (int n0 = 0; n0 < 16; ++n0){
    int n = n0*16 + (lane & 15);
    unsigned c = (unsigned)(wk*64 + ((lane>>4)*16));
    b_rd[n0] = 8192u + n*128 + (c ^ ((n & 7) << 4));
  }
  const f32x4 fzero = {0.f,0.f,0.f,0.f};
  f32x4 acc[16];
  #pragma unroll
  for (int i = 0; i < 16; ++i) acc[i] = fzero;

  auto STAGE = [&](unsigned bufoff, int t){
    char* l = smem + bufoff;
    size_t ka = (size_t)t*256, kb = (size_t)t*128;
    #pragma unroll
    for (int i = 0; i < 2; ++i) gload16(Ab + a_src[i] + ka, l + a_lds[i]);
    #pragma unroll
    for (int i = 0; i < 8; ++i) gload16(Bb + b_src[i] + kb, l + b_lds[i]);
  };
  STAGE(0, 0);
  STAGE(GBUFB, 1);
  asm volatile("s_waitcnt vmcnt(10)" ::: "memory");
  __builtin_amdgcn_s_barrier();
  for (int t = 0; t < T; ++t){
    char* l = smem + (unsigned)(t % 3) * GBUFB;
    if (t + 2 < T) STAGE((unsigned)((t+2)%3)*GBUFB, t+2);
    f32x4 a0 = *(const f32x4*)(l + a_rd0);
    f32x4 a1 = *(const f32x4*)(l + a_rd1);
    union { bf16x8 v; unsigned u[4]; } af;
    af.u[0] = cvt2(a0.x, a0.y);
    af.u[1] = cvt2(a0.z, a0.w);
    af.u[2] = cvt2(a1.x, a1.y);
    af.u[3] = cvt2(a1.z, a1.w);
    #pragma unroll
    for (int n0 = 0; n0 < 16; ++n0){
      bf16x8 bfr = *(const bf16x8*)(l + b_rd[n0]);
      acc[n0] = __builtin_amdgcn_mfma_f32_16x16x32_bf16(af.v, bfr, acc[n0], 0,0,0);
    }
    if (t + 1 < T){
      if (t + 2 < T) asm volatile("s_waitcnt vmcnt(10)" ::: "memory");
      else           asm volatile("s_waitcnt vmcnt(0)" ::: "memory");
      __builtin_amdgcn_s_barrier();
    }
  }
  __syncthreads();
  float* red = (float*)smem;
  if (wk == 1){
    #pragma unroll
    for (int n0 = 0; n0 < 16; ++n0)
      #pragma unroll
      for (int q = 0; q < 4; ++q){
        int row = wm*16 + ((lane>>4)<<2) + q;
        int col = n0*16 + (lane & 15);
        red[row*256 + col] = acc[n0][q];
      }
  }
  __syncthreads();
  if (wk == 0){
    #pragma unroll
    for (int n0 = 0; n0 < 16; ++n0)
      #pragma unroll
      for (int q = 0; q < 4; ++q){
        int row = wm*16 + ((lane>>4)<<2) + q;
        int col = n0*16 + (lane & 15);
        float v = acc[n0][q] + red[row*256 + col];
        partials[((size_t)split*1024 + mtile*32 + row)*256 + col] = v;
      }
  }
}

__global__ void prep_wt(const float* w0, const float* w1, const float* w2,
                        bf16_t* o0, bf16_t* o1, bf16_t* o2){
  const float* w = (blockIdx.x == 0) ? w0 : (blockIdx.x == 1) ? w1 : w2;
  bf16_t*      o = (blockIdx.x == 0) ? o0 : (blockIdx.x == 1) ? o1 : o2;
  int tid = threadIdx.x;
  int n = tid >> 1, h = tid & 1;
  unsigned wr[32] __attribute__((aligned(16)));
  #pragma unroll
  for (int r = 0; r < 32; ++r){
    float v0 = w[(h*64 + 2*r    )*128 + n];
    float v1 = w[(h*64 + 2*r + 1)*128 + n];
    wr[r] = cvt2(v0, v1);
  }
  u32x4* dst = (u32x4*)(o + n*128 + h*64);
  #pragma unroll
  for (int i = 0; i < 8; ++i) dst[i] = *(const u32x4*)&wr[i*4];
}

__global__ void reduce_users(const float* __restrict__ partials, float* __restrict__ out){
  int idx = blockIdx.x * 256 + threadIdx.x;
  int b = idx >> 8, n = idx & 255;
  float s = 0.f;
  #pragma unroll
  for (int k = 0; k < 8; ++k) s += partials[((size_t)k*1024 + b)*256 + n];
  if (n < 128) out[((size_t)(3*PP) + b)*128 + n]           = s;
  else         out[((size_t)(3*PP) + BB + b)*128 + (n-128)] = s;
}

extern "C" void kernel_launch(void* const* d_in, const int* in_sizes, int n_in,
                              void* d_out, int out_size, void* d_ws, size_t ws_size,
                              hipStream_t stream){
  const float* pe   = (const float*)d_in[0];
  const float* wgeo = (const float*)d_in[1];
  const float* bgeo = (const float*)d_in[2];
  const float* wseq = (const float*)d_in[3];
  const float* bseq = (const float*)d_in[4];
  const float* wcol = (const float*)d_in[5];
  const float* bcol = (const float*)d_in[6];
  const float* hup  = (const float*)d_in[7];
  const float* hpu  = (const float*)d_in[8];
  const float* hsrc = (const float*)d_in[9];
  const float* htar = (const float*)d_in[10];
  const float* geo  = (const float*)d_in[11];
  const int*   uidx = (const int*)d_in[12];
  float* out = (float*)d_out;

  char* w = (char*)d_ws;
  const size_t MB = 1024*1024;
  float*  x_f32 = (float*)(w);
  float*  g_f32 = (float*)(w + 4*MB);
  float*  s_f32 = (float*)(w + 8*MB);
  bf16_t* xT    = (bf16_t*)(w + 12*MB);
  bf16_t* gT    = (bf16_t*)(w + 14*MB);
  bf16_t* sT    = (bf16_t*)(w + 16*MB);
  bf16_t* upT   = (bf16_t*)(w + 18*MB);
  bf16_t* tarT  = (bf16_t*)(w + 19*MB);
  bf16_t* b5t   = (bf16_t*)(w + 20*MB);
  bf16_t* wtg   = (bf16_t*)(w + 24*MB);
  bf16_t* wts   = (bf16_t*)(w + 24*MB + 32768);
  bf16_t* wtc   = (bf16_t*)(w + 24*MB + 65536);
  float*  parts = (float*)(w + 25*MB);

  prep_wt<<<3, 256, 0, stream>>>(wgeo, wseq, wcol, wtg, wts, wtc);

  // gates: gate = pe * sigmoid(pe@W + b)
  Job jg{pe, wtg, pe, bgeo, g_f32, gT, PP, 1.f, 128, 256, 1};
  Job js{pe, wts, pe, bseq, s_f32, sT, PP, 1.f, 128, 256, 1};
  Job jc{pe, wtc, pe, bcol, x_f32, xT, PP, 1.f, 128, 256, 1};
  gemm_gates<<<768, 256, 0, stream>>>(jg, js, jc);

  // phase B (dual-window kernel, K=8192): tmp_up = HG_up@x ;
  // geo_pois = g + 0.4*(geo@g) ; tmp_tar = HG_poi_tar@s
  Job j1 {hup,  xT, nullptr, nullptr, nullptr,               upT,                  UU, 1.f,  PP, 128, 0};
  Job j3 {geo,  gT, g_f32,   nullptr, out + (size_t)PP*128,  b5t + (size_t)128*PP, PP, 0.4f, PP, 256, 0};
  Job j4a{htar, sT, nullptr, nullptr, nullptr,               tarT,                 EE, 1.f,  PP, 128, 0};
  gemm_rs2<<<512, 256, 0, stream>>>(j1, j3, j4a);

  // phase C (verified gemm_rs, K=4096): hg_pois = x + HG_pu@tmp_up ;
  // trans_pois = s + src@tmp_tar
  Job j2 {hpu,  upT,  x_f32, nullptr, out,                     b5t,     PP, 1.f, UU, 256, 0};
  Job j4b{hsrc, tarT, s_f32, nullptr, out + (size_t)2*PP*128,  nullptr, 0,  1.f, EE, 256, 0};
  Job jd = j4b; jd.nb = 0;
  gemm_rs<<<512, 256, 0, stream>>>(j2, j4b, jd);

  // users: HG_up[user_idx] @ [hg_pois | geo_pois], split-K=8 then deterministic reduce
  gemm_gather<<<256, 256, 0, stream>>>(hup, uidx, b5t, parts);
  reduce_users<<<1024, 256, 0, stream>>>(parts, out);
}